// Round 8
// baseline (1910.887 us; speedup 1.0000x reference)
//
#include <hip/hip_runtime.h>
#include <hip/hip_bf16.h>

typedef unsigned short u16;
typedef unsigned int   u32;
typedef unsigned long long u64;
typedef __attribute__((ext_vector_type(4)))  float  f32x4;
typedef __attribute__((ext_vector_type(8)))  short  short8;
typedef __attribute__((ext_vector_type(16))) float  f32x16;

#define MB     256
#define SRCT   120
#define DECT   24
#define NSTEP  144
#define DIN    216
#define HDIM   1024
#define KXP    224
#define KA     1248
#define NGATE  4096
#define OUTD   216
#define NWG    256

// ---- ws layout (bytes) ----
// srcbfT [t120][g8][oct28][m32][8] bf16 ; HT 2x[g8][hoct128][m32][8] bf16
// XdT [g8][oct28][m32][8] bf16 ; Wcat [4096][1248] bf16 ; Wo [216][1024] bf16
#define OFF_SRCBF 0u
#define OFF_H     13762560u
#define OFF_XDEC  14811136u
#define OFF_WCAT  14925824u
#define OFF_WO    25149440u
#define OFF_BAR   25591808u      // 8 groups x 64 u32 (slots packed in 128 B line)

__device__ __forceinline__ u16 f2bf(float f) {
    union { float f; unsigned v; } c; c.f = f;
    return (u16)((c.v + 0x7FFFu + ((c.v >> 16) & 1u)) >> 16);
}
__device__ __forceinline__ float sigm(float x)  { return 1.0f / (1.0f + __expf(-x)); }
__device__ __forceinline__ float tanh_(float x) { return 1.0f - 2.0f / (1.0f + __expf(2.0f * x)); }

__device__ __forceinline__ u64 aload(const u64* p) {
    return __hip_atomic_load(p, __ATOMIC_RELAXED, __HIP_MEMORY_SCOPE_AGENT);
}
__device__ __forceinline__ void astore(u64* p, u64 v) {
    __hip_atomic_store(p, v, __ATOMIC_RELAXED, __HIP_MEMORY_SCOPE_AGENT);
}

// 32-WG group barrier: per-WG slot (packed line) + 32-lane parallel poll.
__device__ __forceinline__ void gbar(u32* gslots, int s, u32 gen) {
    __syncthreads();   // drains vmcnt -> write-through stores are at L3
    if (threadIdx.x == 0)
        __hip_atomic_store(gslots + s, gen, __ATOMIC_RELAXED, __HIP_MEMORY_SCOPE_AGENT);
    if (threadIdx.x < 64) {
        const int idx = threadIdx.x & 31;
        while (__hip_atomic_load(gslots + idx, __ATOMIC_RELAXED, __HIP_MEMORY_SCOPE_AGENT) < gen)
            __builtin_amdgcn_s_sleep(1);
    }
    __syncthreads();
}

// ---------------- prep: fp32 -> bf16, transposed comm layouts ----------------
__global__ void prep_kernel(const float* __restrict__ src,
                            const float* __restrict__ W_ih,
                            const float* __restrict__ W_hh,
                            const float* __restrict__ W_out,
                            u16* __restrict__ srcbf, u16* __restrict__ H,
                            u16* __restrict__ Xd,    u16* __restrict__ Wcat,
                            u16* __restrict__ Wo,    u32* __restrict__ bar) {
    const int nS  = SRCT * 8 * 28 * 256;
    const int nW  = NGATE * KA;
    const int nWo = OUTD * HDIM;
    const int nH  = MB * HDIM;
    const int nXd = 8 * 28 * 256;
    const int nB  = 8 * 64;
    const int total = nS + nW + nWo + nH + nXd + nB;
    for (int i = blockIdx.x * blockDim.x + threadIdx.x; i < total; i += gridDim.x * blockDim.x) {
        if (i < nS) {
            int r = i & 255, i2 = i >> 8;
            int m = r >> 3, e = r & 7;
            int oct = i2 % 28, q = i2 / 28;
            int gi = q & 7, t = q >> 3;
            int col = oct * 8 + e, b = gi * 32 + m;
            srcbf[i] = (col < DIN) ? f2bf(src[((size_t)b * SRCT + t) * DIN + col]) : (u16)0;
        } else if (i < nS + nW) {
            int j = i - nS;
            int r = j / KA, col = j % KA;
            u16 v = 0;
            if (col < DIN)       v = f2bf(W_ih[(size_t)r * DIN + col]);
            else if (col >= KXP) v = f2bf(W_hh[(size_t)r * HDIM + (col - KXP)]);
            Wcat[j] = v;
        } else if (i < nS + nW + nWo) {
            int j = i - nS - nW;
            Wo[j] = f2bf(W_out[j]);
        } else if (i < nS + nW + nWo + nH) {
            H[i - nS - nW - nWo] = 0;
        } else if (i < nS + nW + nWo + nH + nXd) {
            Xd[i - nS - nW - nWo - nH] = 0;
        } else {
            bar[i - nS - nW - nWo - nH - nXd] = 0;
        }
    }
}

// ---------------- persistent LSTM ----------------
// group g = bid&7: batches [g*32,+32). slice s = bid>>3: h-cols [s*32,+32)
// x 4 gates. Waves K-split; B pinned in regs; A-frags loaded DIRECTLY from
// global transposed buffers (no LDS staging).
__global__ void __launch_bounds__(256, 1)
lstm_persist(const u16* __restrict__ srcbf, u16* __restrict__ H,
             u16* __restrict__ Xd, const u16* __restrict__ Wcat,
             const u16* __restrict__ Wo,
             const float* __restrict__ b_ih, const float* __restrict__ b_hh,
             const float* __restrict__ b_out,
             float* __restrict__ dout, u32* __restrict__ bar)
{
    __shared__ __align__(16) float G2[16 * 32 * 36];   // [slab16][col32][b36] 73,728 B
    __shared__ __align__(16) u16  Hx[4 * 32 * 8];      // exchange tile 2 KB

    const int bid  = blockIdx.x;
    const int g    = bid & 7;
    const int s    = bid >> 3;
    const int b0   = g * 32;
    const int tid  = threadIdx.x;
    const int p    = tid >> 6;
    const int lane = tid & 63;
    const int l31  = lane & 31;
    const int kg   = lane >> 5;

    u32* gslots = bar + g * 64;

    // K-split: waves cover 20/20/19/19 k-tiles
    const int ktb = p * 20 - (p == 3 ? 1 : 0);
    const int ktc = (p < 2) ? 20 : 19;

    // ---- pin B for all 4 gates, this wave's k-range ----
    short8 Bfrag[4][20];
#pragma unroll
    for (int gg = 0; gg < 4; ++gg) {
        const u16* pw = Wcat + (size_t)(gg * 1024 + s * 32 + l31) * KA + kg * 8;
#pragma unroll
        for (int j = 0; j < 20; ++j) {
            int kt = ktb + j; if (kt > 77) kt = 77;
            Bfrag[gg][j] = *(const short8*)(pw + kt * 16);
        }
    }

    // pointwise mapping: thread -> (col cs, 4 batches bq*4..)
    const int cs = tid & 31;
    const int bq = tid >> 5;
    float creg[4] = {0.f, 0.f, 0.f, 0.f};
    const int hcg = s * 32 + cs;
    const float bI  = b_ih[hcg]        + b_hh[hcg];
    const float bF  = b_ih[1024 + hcg] + b_hh[1024 + hcg];
    const float bG_ = b_ih[2048 + hcg] + b_hh[2048 + hcg];
    const float bO  = b_ih[3072 + hcg] + b_hh[3072 + hcg];
    const float bOutv = (s < 7 && hcg < OUTD) ? b_out[hcg] : 0.f;

    u32 gen = 0;

    for (int t = 0; t < NSTEP; ++t) {
        const u64* Hc64 = (const u64*)(H + (size_t)(t & 1) * (MB * HDIM) + (size_t)g * 32768);
        u16*       HTn  = H + (size_t)((t + 1) & 1) * (MB * HDIM);
        const bool enc  = (t <= SRCT);
        const int  tt   = (t < SRCT) ? t : (SRCT - 1);
        const u16* xsb  = srcbf + (size_t)(tt * 8 + g) * 28 * 256;
        const u64* Xd64 = (const u64*)Xd + (size_t)g * 1792;

        // ---- gate GEMM: direct global A-frags x pinned B ----
        f32x16 acc[4] = {f32x16{}, f32x16{}, f32x16{}, f32x16{}};
#pragma unroll
        for (int j = 0; j < 20; ++j) {
            if (j < ktc) {
                const int kt   = ktb + j;
                const int oct2 = 2 * kt + kg;
                short8 af;
                if (oct2 < 28) {
                    if (enc) {
                        af = *(const short8*)(xsb + ((size_t)oct2 * 32 + l31) * 8);
                    } else {
                        union { short8 s8; u64 q[2]; } ua;
                        const u64* xp = Xd64 + ((size_t)oct2 * 32 + l31) * 2;
                        ua.q[0] = aload(xp); ua.q[1] = aload(xp + 1);
                        af = ua.s8;
                    }
                } else {
                    union { short8 s8; u64 q[2]; } ua;
                    const u64* hp = Hc64 + ((size_t)(oct2 - 28) * 32 + l31) * 2;
                    ua.q[0] = aload(hp); ua.q[1] = aload(hp + 1);
                    af = ua.s8;
                }
                acc[0] = __builtin_amdgcn_mfma_f32_32x32x16_bf16(af, Bfrag[0][j], acc[0], 0, 0, 0);
                acc[1] = __builtin_amdgcn_mfma_f32_32x32x16_bf16(af, Bfrag[1][j], acc[1], 0, 0, 0);
                acc[2] = __builtin_amdgcn_mfma_f32_32x32x16_bf16(af, Bfrag[2][j], acc[2], 0, 0, 0);
                acc[3] = __builtin_amdgcn_mfma_f32_32x32x16_bf16(af, Bfrag[3][j], acc[3], 0, 0, 0);
            }
        }
        // partials -> G2[slab=gg*4+p][col][batch]
#pragma unroll
        for (int gg = 0; gg < 4; ++gg) {
#pragma unroll
            for (int rq = 0; rq < 4; ++rq) {
                f32x4 v;
                v[0] = acc[gg][rq * 4 + 0]; v[1] = acc[gg][rq * 4 + 1];
                v[2] = acc[gg][rq * 4 + 2]; v[3] = acc[gg][rq * 4 + 3];
                *(f32x4*)&G2[(size_t)((gg * 4 + p) * 32 + l31) * 36 + rq * 8 + kg * 4] = v;
            }
        }
        __syncthreads();

        // ---- pointwise cell ----
        {
            f32x4 sg[4];
#pragma unroll
            for (int gg = 0; gg < 4; ++gg) {
                f32x4 a = *(const f32x4*)&G2[(size_t)((gg * 4 + 0) * 32 + cs) * 36 + bq * 4];
#pragma unroll
                for (int pp = 1; pp < 4; ++pp)
                    a += *(const f32x4*)&G2[(size_t)((gg * 4 + pp) * 32 + cs) * 36 + bq * 4];
                sg[gg] = a;
            }
#pragma unroll
            for (int i = 0; i < 4; ++i) {
                float gi = sg[0][i] + bI, gf = sg[1][i] + bF;
                float gG = sg[2][i] + bG_, go = sg[3][i] + bO;
                float c = sigm(gf) * creg[i] + sigm(gi) * tanh_(gG);
                creg[i] = c;
                Hx[(cs >> 3) * 256 + (bq * 4 + i) * 8 + (cs & 7)] = f2bf(sigm(go) * tanh_(c));
            }
        }
        __syncthreads();
        // coalesced write-through of this WG's h slice (4 octets x 32 batches)
        {
            u64 v = ((const u64*)Hx)[tid];
            astore((u64*)HTn + (size_t)g * 8192 + s * 256 + tid, v);
        }
        gbar(gslots, s, ++gen);

        // ---- decoder: out = h_new @ Wo^T (direct h loads), x exchange ----
        if (t >= SRCT) {
            const int d = t - SRCT;
            const u64* Hn64 = (const u64*)HTn + (size_t)g * 8192;
            if (s < 7) {
                f32x16 oacc = {};
                const int orow = (s * 32 + l31 < OUTD) ? (s * 32 + l31) : (OUTD - 1);
                const u16* wob = Wo + (size_t)orow * HDIM + kg * 8;
#pragma unroll
                for (int j = 0; j < 16; ++j) {
                    int kt = p * 16 + j;
                    union { short8 s8; u64 q[2]; } ua;
                    const u64* hp = Hn64 + ((size_t)(2 * kt + kg) * 32 + l31) * 2;
                    ua.q[0] = aload(hp); ua.q[1] = aload(hp + 1);
                    short8 bf = *(const short8*)(wob + (size_t)kt * 16);
                    oacc = __builtin_amdgcn_mfma_f32_32x32x16_bf16(ua.s8, bf, oacc, 0, 0, 0);
                }
#pragma unroll
                for (int rq = 0; rq < 4; ++rq) {
                    f32x4 v;
                    v[0] = oacc[rq * 4 + 0]; v[1] = oacc[rq * 4 + 1];
                    v[2] = oacc[rq * 4 + 2]; v[3] = oacc[rq * 4 + 3];
                    *(f32x4*)&G2[(size_t)(p * 32 + l31) * 36 + rq * 8 + kg * 4] = v;
                }
            }
            __syncthreads();
            if (s < 7) {
                const int  ocol = s * 32 + cs;
                const bool real = ocol < OUTD;
                f32x4 S = *(const f32x4*)&G2[(size_t)(0 * 32 + cs) * 36 + bq * 4];
#pragma unroll
                for (int pp = 1; pp < 4; ++pp)
                    S += *(const f32x4*)&G2[(size_t)(pp * 32 + cs) * 36 + bq * 4];
#pragma unroll
                for (int i = 0; i < 4; ++i) {
                    float v = real ? (S[i] + bOutv) : 0.f;
                    Hx[(cs >> 3) * 256 + (bq * 4 + i) * 8 + (cs & 7)] = real ? f2bf(v) : (u16)0;
                    if (real)
                        dout[(size_t)(b0 + bq * 4 + i) * (DECT * OUTD) + (size_t)d * OUTD + ocol] = v;
                }
            }
            __syncthreads();
            if (s < 7) {
                u64 v = ((const u64*)Hx)[tid];
                astore((u64*)Xd + (size_t)g * 1792 + s * 256 + tid, v);
            }
            gbar(gslots, s, ++gen);
        }
    }
}

extern "C" void kernel_launch(void* const* d_in, const int* in_sizes, int n_in,
                              void* d_out, int out_size, void* d_ws, size_t ws_size,
                              hipStream_t stream) {
    const float* src   = (const float*)d_in[0];
    // d_in[1] = tgt (unused in eval forward)
    const float* W_ih  = (const float*)d_in[2];
    const float* W_hh  = (const float*)d_in[3];
    const float* b_ih  = (const float*)d_in[4];
    const float* b_hh  = (const float*)d_in[5];
    const float* W_out = (const float*)d_in[6];
    const float* b_out = (const float*)d_in[7];
    float* out = (float*)d_out;

    char* ws = (char*)d_ws;
    u16* srcbf = (u16*)(ws + OFF_SRCBF);
    u16* H     = (u16*)(ws + OFF_H);
    u16* Xd    = (u16*)(ws + OFF_XDEC);
    u16* Wcat  = (u16*)(ws + OFF_WCAT);
    u16* Wo    = (u16*)(ws + OFF_WO);
    u32* bar   = (u32*)(ws + OFF_BAR);

    hipLaunchKernelGGL(prep_kernel, dim3(2048), dim3(256), 0, stream,
                       src, W_ih, W_hh, W_out, srcbf, H, Xd, Wcat, Wo, bar);

    hipLaunchKernelGGL(lstm_persist, dim3(NWG), dim3(256), 0, stream,
                       srcbf, H, Xd, Wcat, Wo, b_ih, b_hh, b_out, out, bar);
}

// Round 9
// 947.885 us; speedup vs baseline: 2.0159x; 2.0159x over previous
//
#include <hip/hip_runtime.h>
#include <hip/hip_bf16.h>

typedef unsigned short u16;
typedef unsigned int   u32;
typedef unsigned long long u64;
typedef __attribute__((ext_vector_type(4)))  float  f32x4;
typedef __attribute__((ext_vector_type(8)))  short  short8;
typedef __attribute__((ext_vector_type(16))) float  f32x16;

#define MB     256
#define SRCT   120
#define DECT   24
#define NSTEP  144
#define DIN    216
#define HDIM   1024
#define KXP    224
#define KA     1248
#define NGATE  4096
#define OUTD   216
#define NWG    256

// ---- ws layout (bytes) ----
// srcbfT [t120][g8][oct28][m32][8] bf16 ; HT 2x[g8][hoct128][m32][8] bf16
// XdT [g8][oct28][m32][8] bf16 ; Wcat [4096][1248] bf16 ; Wo [216][1024] bf16
#define OFF_SRCBF 0u
#define OFF_H     13762560u
#define OFF_XDEC  14811136u
#define OFF_WCAT  14925824u
#define OFF_WO    25149440u
#define OFF_BAR   25591808u      // 8 groups x 64 u32

__device__ __forceinline__ u16 f2bf(float f) {
    union { float f; unsigned v; } c; c.f = f;
    return (u16)((c.v + 0x7FFFu + ((c.v >> 16) & 1u)) >> 16);
}
__device__ __forceinline__ float sigm(float x)  { return 1.0f / (1.0f + __expf(-x)); }
__device__ __forceinline__ float tanh_(float x) { return 1.0f - 2.0f / (1.0f + __expf(2.0f * x)); }

__device__ __forceinline__ void astore(u64* p, u64 v) {
    __hip_atomic_store(p, v, __ATOMIC_RELAXED, __HIP_MEMORY_SCOPE_AGENT);
}

// async global->LDS DMA, 16 B/lane. AUX: 0 = cached; 17 = SC0|SC1 (read
// through the device coherence point — required for cross-XCD-produced data).
template <int AUX>
__device__ __forceinline__ void dma16(const u16* g, u16* l) {
    __builtin_amdgcn_global_load_lds(
        (const __attribute__((address_space(1))) void*)g,
        (__attribute__((address_space(3))) void*)l, 16, 0, AUX);
}

// split barrier: arrive (drains stores via __syncthreads) / wait (32-lane poll)
__device__ __forceinline__ void bar_arrive(u32* gslots, int s, u32 gen) {
    __syncthreads();
    if (threadIdx.x == 0)
        __hip_atomic_store(gslots + s, gen, __ATOMIC_RELAXED, __HIP_MEMORY_SCOPE_AGENT);
}
__device__ __forceinline__ void bar_wait(u32* gslots, u32 gen) {
    if (threadIdx.x < 64) {
        const int idx = threadIdx.x & 31;
        while (__hip_atomic_load(gslots + idx, __ATOMIC_RELAXED, __HIP_MEMORY_SCOPE_AGENT) < gen)
            __builtin_amdgcn_s_sleep(1);
    }
    __syncthreads();
}

// ---------------- prep: fp32 -> bf16, transposed comm layouts ----------------
__global__ void prep_kernel(const float* __restrict__ src,
                            const float* __restrict__ W_ih,
                            const float* __restrict__ W_hh,
                            const float* __restrict__ W_out,
                            u16* __restrict__ srcbf, u16* __restrict__ H,
                            u16* __restrict__ Xd,    u16* __restrict__ Wcat,
                            u16* __restrict__ Wo,    u32* __restrict__ bar) {
    const int nS  = SRCT * 8 * 28 * 256;
    const int nW  = NGATE * KA;
    const int nWo = OUTD * HDIM;
    const int nH  = MB * HDIM;
    const int nXd = 8 * 28 * 256;
    const int nB  = 8 * 64;
    const int total = nS + nW + nWo + nH + nXd + nB;
    for (int i = blockIdx.x * blockDim.x + threadIdx.x; i < total; i += gridDim.x * blockDim.x) {
        if (i < nS) {
            int r = i & 255, i2 = i >> 8;
            int m = r >> 3, e = r & 7;
            int oct = i2 % 28, q = i2 / 28;
            int gi = q & 7, t = q >> 3;
            int col = oct * 8 + e, b = gi * 32 + m;
            srcbf[i] = (col < DIN) ? f2bf(src[((size_t)b * SRCT + t) * DIN + col]) : (u16)0;
        } else if (i < nS + nW) {
            int j = i - nS;
            int r = j / KA, col = j % KA;
            u16 v = 0;
            if (col < DIN)       v = f2bf(W_ih[(size_t)r * DIN + col]);
            else if (col >= KXP) v = f2bf(W_hh[(size_t)r * HDIM + (col - KXP)]);
            Wcat[j] = v;
        } else if (i < nS + nW + nWo) {
            int j = i - nS - nW;
            Wo[j] = f2bf(W_out[j]);
        } else if (i < nS + nW + nWo + nH) {
            H[i - nS - nW - nWo] = 0;
        } else if (i < nS + nW + nWo + nH + nXd) {
            Xd[i - nS - nW - nWo - nH] = 0;
        } else {
            bar[i - nS - nW - nWo - nH - nXd] = 0;
        }
    }
}

// ---------------- persistent LSTM ----------------
// group g = bid&7: batches [g*32,+32). slice s = bid>>3: h-cols [s*32,+32)
// x 4 gates. Waves K-split; B pinned in regs; A staged in LDS via async DMA.
__global__ void __launch_bounds__(256, 1)
lstm_persist(const u16* __restrict__ srcbf, u16* __restrict__ H,
             u16* __restrict__ Xd, const u16* __restrict__ Wcat,
             const u16* __restrict__ Wo,
             const float* __restrict__ b_ih, const float* __restrict__ b_hh,
             const float* __restrict__ b_out,
             float* __restrict__ dout, u32* __restrict__ bar)
{
    __shared__ __align__(16) u16  Ach[156 * 32 * 8];   // [oct][m][8]  79,872 B
    __shared__ __align__(16) float G2[16 * 32 * 36];   // [slab][col][b36] 73,728 B
    __shared__ __align__(16) u16  Hx[4 * 32 * 8];      // transpose tile 2 KB

    const int bid  = blockIdx.x;
    const int g    = bid & 7;
    const int s    = bid >> 3;
    const int b0   = g * 32;
    const int tid  = threadIdx.x;
    const int p    = tid >> 6;
    const int lane = tid & 63;
    const int l31  = lane & 31;
    const int kg   = lane >> 5;

    u32* gslots = bar + g * 64;
    const u16* Xdg = Xd + (size_t)g * 7168;

    // K-split: waves cover 20/20/19/19 k-tiles
    const int ktb = p * 20 - (p == 3 ? 1 : 0);
    const int ktc = (p < 2) ? 20 : 19;

    // ---- pin B for all 4 gates, this wave's k-range ----
    short8 Bfrag[4][20];
#pragma unroll
    for (int gg = 0; gg < 4; ++gg) {
        const u16* pw = Wcat + (size_t)(gg * 1024 + s * 32 + l31) * KA + kg * 8;
#pragma unroll
        for (int j = 0; j < 20; ++j) {
            int kt = ktb + j; if (kt > 77) kt = 77;
            Bfrag[gg][j] = *(const short8*)(pw + kt * 16);
        }
    }

    // pointwise mapping: thread -> (col cs, 4 batches bq*4..)
    const int cs = tid & 31;
    const int bq = tid >> 5;
    float creg[4] = {0.f, 0.f, 0.f, 0.f};
    const int hcg = s * 32 + cs;
    const float bI  = b_ih[hcg]        + b_hh[hcg];
    const float bF  = b_ih[1024 + hcg] + b_hh[1024 + hcg];
    const float bG_ = b_ih[2048 + hcg] + b_hh[2048 + hcg];
    const float bO  = b_ih[3072 + hcg] + b_hh[3072 + hcg];
    const float bOutv = (s < 7 && hcg < OUTD) ? b_out[hcg] : 0.f;

    u32 gen = 0;

    // ---- pre-loop: stage x(t=0) + h0 ----
    {
        const u16* xsb0 = srcbf + (size_t)g * 7168;   // t = 0
#pragma unroll
        for (int j = 0; j < 4; ++j) {
            int idx = p + 4 * j;
            if (idx < 14) dma16<0>(xsb0 + idx * 512 + lane * 8, Ach + idx * 512);
        }
        const u16* h0 = H + (size_t)g * 32768;        // buf0 (zeros)
#pragma unroll
        for (int j = 0; j < 16; ++j) {
            int idx = p * 16 + j;
            dma16<17>(h0 + idx * 512 + lane * 8, Ach + 7168 + idx * 512);
        }
    }
    __syncthreads();

    for (int t = 0; t < NSTEP; ++t) {
        u16* HTn = H + (size_t)((t + 1) & 1) * (MB * HDIM);
        const u16* hnext = HTn + (size_t)g * 32768;

        // ---- gate GEMM from Ach x pinned B ----
        f32x16 acc[4] = {f32x16{}, f32x16{}, f32x16{}, f32x16{}};
#pragma unroll
        for (int j = 0; j < 20; ++j) {
            if (j < ktc) {
                const int oct = 2 * (ktb + j) + kg;
                short8 af = *(const short8*)(Ach + (size_t)(oct * 32 + l31) * 8);
                acc[0] = __builtin_amdgcn_mfma_f32_32x32x16_bf16(af, Bfrag[0][j], acc[0], 0, 0, 0);
                acc[1] = __builtin_amdgcn_mfma_f32_32x32x16_bf16(af, Bfrag[1][j], acc[1], 0, 0, 0);
                acc[2] = __builtin_amdgcn_mfma_f32_32x32x16_bf16(af, Bfrag[2][j], acc[2], 0, 0, 0);
                acc[3] = __builtin_amdgcn_mfma_f32_32x32x16_bf16(af, Bfrag[3][j], acc[3], 0, 0, 0);
            }
        }
#pragma unroll
        for (int gg = 0; gg < 4; ++gg) {
#pragma unroll
            for (int rq = 0; rq < 4; ++rq) {
                f32x4 v;
                v[0] = acc[gg][rq * 4 + 0]; v[1] = acc[gg][rq * 4 + 1];
                v[2] = acc[gg][rq * 4 + 2]; v[3] = acc[gg][rq * 4 + 3];
                *(f32x4*)&G2[(size_t)((gg * 4 + p) * 32 + l31) * 36 + rq * 8 + kg * 4] = v;
            }
        }
        __syncthreads();

        // ---- pointwise cell ----
        {
            f32x4 sg[4];
#pragma unroll
            for (int gg = 0; gg < 4; ++gg) {
                f32x4 a = *(const f32x4*)&G2[(size_t)((gg * 4 + 0) * 32 + cs) * 36 + bq * 4];
#pragma unroll
                for (int pp = 1; pp < 4; ++pp)
                    a += *(const f32x4*)&G2[(size_t)((gg * 4 + pp) * 32 + cs) * 36 + bq * 4];
                sg[gg] = a;
            }
#pragma unroll
            for (int i = 0; i < 4; ++i) {
                float gi = sg[0][i] + bI, gf = sg[1][i] + bF;
                float gG = sg[2][i] + bG_, go = sg[3][i] + bO;
                float c = sigm(gf) * creg[i] + sigm(gi) * tanh_(gG);
                creg[i] = c;
                Hx[(cs >> 3) * 256 + (bq * 4 + i) * 8 + (cs & 7)] = f2bf(sigm(go) * tanh_(c));
            }
        }
        __syncthreads();
        // coalesced write-through of this WG's h slice
        astore((u64*)HTn + (size_t)g * 8192 + s * 256 + tid, ((const u64*)Hx)[tid]);

        if (t < SRCT) {
            bar_arrive(gslots, s, ++gen);
            // x-DMA for t+1 (known), hidden behind the poll
            int tt2 = (t + 1 < SRCT) ? (t + 1) : (SRCT - 1);
            const u16* xsb2 = srcbf + (size_t)(tt2 * 8 + g) * 7168 / 8 * 8;
            xsb2 = srcbf + (size_t)(tt2 * 8 + g) * 28 * 256;
#pragma unroll
            for (int j = 0; j < 4; ++j) {
                int idx = p + 4 * j;
                if (idx < 14) dma16<0>(xsb2 + idx * 512 + lane * 8, Ach + idx * 512);
            }
            bar_wait(gslots, gen);
            // h-DMA (h_{t+1}, coherent)
#pragma unroll
            for (int j = 0; j < 16; ++j) {
                int idx = p * 16 + j;
                dma16<17>(hnext + idx * 512 + lane * 8, Ach + 7168 + idx * 512);
            }
            __syncthreads();
        } else {
            const int d = t - SRCT;
            bar_arrive(gslots, s, ++gen);
            bar_wait(gslots, gen);
            // h-DMA (h_{t+1}) — serves out-GEMM now and gate GEMM next step
#pragma unroll
            for (int j = 0; j < 16; ++j) {
                int idx = p * 16 + j;
                dma16<17>(hnext + idx * 512 + lane * 8, Ach + 7168 + idx * 512);
            }
            __syncthreads();
            // out-GEMM (s<7): out = h_new @ Wo^T
            if (s < 7) {
                f32x16 oacc = {};
                const int orow = (s * 32 + l31 < OUTD) ? (s * 32 + l31) : (OUTD - 1);
                const u16* wob = Wo + (size_t)orow * HDIM + kg * 8;
#pragma unroll
                for (int j = 0; j < 16; ++j) {
                    int kt = p * 16 + j;
                    short8 af = *(const short8*)(Ach + (size_t)((28 + 2 * kt + kg) * 32 + l31) * 8);
                    short8 bf = *(const short8*)(wob + (size_t)kt * 16);
                    oacc = __builtin_amdgcn_mfma_f32_32x32x16_bf16(af, bf, oacc, 0, 0, 0);
                }
#pragma unroll
                for (int rq = 0; rq < 4; ++rq) {
                    f32x4 v;
                    v[0] = oacc[rq * 4 + 0]; v[1] = oacc[rq * 4 + 1];
                    v[2] = oacc[rq * 4 + 2]; v[3] = oacc[rq * 4 + 3];
                    *(f32x4*)&G2[(size_t)(p * 32 + l31) * 36 + rq * 8 + kg * 4] = v;
                }
            }
            __syncthreads();
            if (s < 7) {
                const int  ocol = s * 32 + cs;
                const bool real = ocol < OUTD;
                f32x4 S = *(const f32x4*)&G2[(size_t)(0 * 32 + cs) * 36 + bq * 4];
#pragma unroll
                for (int pp = 1; pp < 4; ++pp)
                    S += *(const f32x4*)&G2[(size_t)(pp * 32 + cs) * 36 + bq * 4];
#pragma unroll
                for (int i = 0; i < 4; ++i) {
                    float v = real ? (S[i] + bOutv) : 0.f;
                    Hx[(cs >> 3) * 256 + (bq * 4 + i) * 8 + (cs & 7)] = real ? f2bf(v) : (u16)0;
                    if (real)
                        dout[(size_t)(b0 + bq * 4 + i) * (DECT * OUTD) + (size_t)d * OUTD + ocol] = v;
                }
            }
            __syncthreads();
            if (s < 7)
                astore((u64*)Xdg + s * 256 + tid, ((const u64*)Hx)[tid]);
            if (t < NSTEP - 1) {
                bar_arrive(gslots, s, ++gen);
                bar_wait(gslots, gen);
                // x-DMA from Xd (coherent) for step t+1
#pragma unroll
                for (int j = 0; j < 4; ++j) {
                    int idx = p + 4 * j;
                    if (idx < 14) dma16<17>(Xdg + idx * 512 + lane * 8, Ach + idx * 512);
                }
                __syncthreads();
            }
        }
    }
}

extern "C" void kernel_launch(void* const* d_in, const int* in_sizes, int n_in,
                              void* d_out, int out_size, void* d_ws, size_t ws_size,
                              hipStream_t stream) {
    const float* src   = (const float*)d_in[0];
    // d_in[1] = tgt (unused in eval forward)
    const float* W_ih  = (const float*)d_in[2];
    const float* W_hh  = (const float*)d_in[3];
    const float* b_ih  = (const float*)d_in[4];
    const float* b_hh  = (const float*)d_in[5];
    const float* W_out = (const float*)d_in[6];
    const float* b_out = (const float*)d_in[7];
    float* out = (float*)d_out;

    char* ws = (char*)d_ws;
    u16* srcbf = (u16*)(ws + OFF_SRCBF);
    u16* H     = (u16*)(ws + OFF_H);
    u16* Xd    = (u16*)(ws + OFF_XDEC);
    u16* Wcat  = (u16*)(ws + OFF_WCAT);
    u16* Wo    = (u16*)(ws + OFF_WO);
    u32* bar   = (u32*)(ws + OFF_BAR);

    hipLaunchKernelGGL(prep_kernel, dim3(2048), dim3(256), 0, stream,
                       src, W_ih, W_hh, W_out, srcbf, H, Xd, Wcat, Wo, bar);

    hipLaunchKernelGGL(lstm_persist, dim3(NWG), dim3(256), 0, stream,
                       srcbf, H, Xd, Wcat, Wo, b_ih, b_hh, b_out, out, bar);
}